// Round 2
// baseline (213.586 us; speedup 1.0000x reference)
//
#include <hip/hip_runtime.h>
#include <hip/hip_bf16.h>
#include <stdint.h>

// Problem: B=2, S=4096, D=1024, H=8, DH=128, W=1024, nb=4, M=B*S=8192
// Pipeline: convert/transpose -> GEMM1 (qkv, writes Q/K row-major + V transposed)
//           -> flash attention per (head, q-block) -> GEMM2 (+bias+residual -> d_out)
//           -> in-place LayerNorm.

typedef float f32x4 __attribute__((ext_vector_type(4)));
typedef __bf16 bf16x8 __attribute__((ext_vector_type(8)));

static __device__ __forceinline__ unsigned short f2bf(float f) {
    // round-to-nearest-even f32 -> bf16 (bit trick; inputs are finite)
    unsigned int u = __builtin_bit_cast(unsigned int, f);
    u += 0x7fffu + ((u >> 16) & 1u);
    return (unsigned short)(u >> 16);
}

static __device__ __forceinline__ unsigned cvt_pk_bf16(float lo, float hi) {
    unsigned r;
    asm("v_cvt_pk_bf16_f32 %0, %1, %2" : "=v"(r) : "v"(lo), "v"(hi));
    return r;  // low16 = bf16(lo), high16 = bf16(hi), RNE
}

static __device__ __forceinline__ void gload_lds16(const void* g, void* l) {
    __builtin_amdgcn_global_load_lds(
        (__attribute__((address_space(1))) void*)(g),
        (__attribute__((address_space(3))) void*)(l), 16, 0, 0);
}

// ---------------- convert f32 -> bf16 (vectorized, G13) ----------------
__global__ __launch_bounds__(256) void k_convert(const float* __restrict__ in,
                                                 unsigned short* __restrict__ out,
                                                 int n4) {
    int i = blockIdx.x * 256 + threadIdx.x;
    if (i >= n4) return;
    float4 v = ((const float4*)in)[i];
    ushort4 o;
    o.x = f2bf(v.x); o.y = f2bf(v.y); o.z = f2bf(v.z); o.w = f2bf(v.w);
    ((ushort4*)out)[i] = o;
}

// ---------------- transpose f32 [R][C] -> bf16 [C][R] ----------------
__global__ __launch_bounds__(256) void k_transpose(const float* __restrict__ in,
                                                   unsigned short* __restrict__ out,
                                                   int R, int C) {
    __shared__ float tile[64][65];  // +1 pad: conflict-free column reads
    const int rt = blockIdx.y * 64, ct = blockIdx.x * 64;
    const int t = threadIdx.x;
#pragma unroll
    for (int i = 0; i < 4; ++i) {
        int fid = i * 256 + t;
        int r = fid >> 4;
        int c = (fid & 15) << 2;
        float4 v = *(const float4*)&in[(size_t)(rt + r) * C + ct + c];
        tile[r][c] = v.x; tile[r][c + 1] = v.y; tile[r][c + 2] = v.z; tile[r][c + 3] = v.w;
    }
    __syncthreads();
#pragma unroll
    for (int i = 0; i < 4; ++i) {
        int fid = i * 256 + t;
        int c = fid >> 4;
        int r0 = (fid & 15) << 2;
        ushort4 o;
        o.x = f2bf(tile[r0][c]);     o.y = f2bf(tile[r0 + 1][c]);
        o.z = f2bf(tile[r0 + 2][c]); o.w = f2bf(tile[r0 + 3][c]);
        *(ushort4*)&out[(size_t)(ct + c) * R + rt + r0] = o;
    }
}

// ---------------- m97-style bf16 GEMM: C = A[M][K] * Bt[N][K]^T ----------------
// MODE 0: qkv projection. n<2048 -> out_qk row-major; n>=2048 -> V written
//         transposed into out_vT[head][d][x] (packed ushort4 along x).
// MODE 1: out projection. out_f[idx] = acc + bias[n] + resid[idx]  (fp32)
template <int MODE>
__global__ __launch_bounds__(256, 2) void k_gemm(
    const unsigned short* __restrict__ A,
    const unsigned short* __restrict__ Bt,
    const float* __restrict__ bias,
    const float* __restrict__ resid,
    unsigned short* __restrict__ out_qk,
    unsigned short* __restrict__ out_vT,
    float* __restrict__ out_f,
    int Kdim)
{
    __shared__ __align__(16) unsigned short Al[128 * 64];  // [m][k] linear (global_load_lds)
    __shared__ __align__(16) unsigned short Bl[128 * 64];  // [n][k] linear
    const int t = threadIdx.x;
    const int wave = t >> 6, lane = t & 63;
    const int wm = wave >> 1, wn = wave & 1;
    const int lr = lane & 15, lg = lane >> 4;
    const int tile_m = blockIdx.y * 128;
    const int tile_n = blockIdx.x * 128;

    f32x4 acc[4][4];
#pragma unroll
    for (int i = 0; i < 4; ++i)
#pragma unroll
        for (int j = 0; j < 4; ++j)
            acc[i][j] = (f32x4){0.f, 0.f, 0.f, 0.f};

    const int srow = lane >> 3;          // 0..7 rows within 1KB chunk
    const int scol = (lane & 7) * 8;     // 8 bf16 = 16B per lane

    for (int kt = 0; kt < Kdim; kt += 64) {
#pragma unroll
        for (int i = 0; i < 4; ++i) {
            int chunk = i * 4 + wave;            // 16 chunks of 1KB (8 rows x 128B)
            int row = chunk * 8 + srow;
            gload_lds16(&A[(size_t)(tile_m + row) * Kdim + kt + scol], &Al[chunk * 512]);
            gload_lds16(&Bt[(size_t)(tile_n + row) * Kdim + kt + scol], &Bl[chunk * 512]);
        }
        __syncthreads();
#pragma unroll
        for (int kk = 0; kk < 2; ++kk) {
            bf16x8 af[4], bfr[4];
#pragma unroll
            for (int mi = 0; mi < 4; ++mi)
                af[mi] = *(const bf16x8*)&Al[(wm * 64 + mi * 16 + lr) * 64 + kk * 32 + lg * 8];
#pragma unroll
            for (int ni = 0; ni < 4; ++ni)
                bfr[ni] = *(const bf16x8*)&Bl[(wn * 64 + ni * 16 + lr) * 64 + kk * 32 + lg * 8];
#pragma unroll
            for (int mi = 0; mi < 4; ++mi)
#pragma unroll
                for (int ni = 0; ni < 4; ++ni)
                    acc[mi][ni] = __builtin_amdgcn_mfma_f32_16x16x32_bf16(af[mi], bfr[ni], acc[mi][ni], 0, 0, 0);
        }
        __syncthreads();
    }

    // epilogue: D row = (lane>>4)*4 + r, col = lane&15 (measured m89/m91 layout)
#pragma unroll
    for (int ni = 0; ni < 4; ++ni) {
        int n = tile_n + wn * 64 + ni * 16 + lr;
        float bv = bias[n];
#pragma unroll
        for (int mi = 0; mi < 4; ++mi) {
            int m0 = tile_m + wm * 64 + mi * 16 + lg * 4;
            f32x4 v = acc[mi][ni];
            if (MODE == 0) {
                if (n < 2048) {          // Q,K region: row-major [m][2048]
#pragma unroll
                    for (int r = 0; r < 4; ++r)
                        out_qk[(size_t)(m0 + r) * 2048 + n] = f2bf(v[r] + bv);
                } else {                 // V region: write transposed [head][d][x]
                    int hd = (n - 2048) >> 7;
                    int dd = (n - 2048) & 127;
                    int bn = m0 >> 10;           // window index b*nb+nblk
                    int x0 = m0 & 1023;          // token-in-window; 4 consecutive
                    ushort4 o;
                    o.x = f2bf(v[0] + bv); o.y = f2bf(v[1] + bv);
                    o.z = f2bf(v[2] + bv); o.w = f2bf(v[3] + bv);
                    *(ushort4*)&out_vT[((size_t)(bn * 8 + hd) * 128 + dd) * 1024 + x0] = o;
                }
            } else {
#pragma unroll
                for (int r = 0; r < 4; ++r) {
                    size_t idx = (size_t)(m0 + r) * 1024 + n;
                    out_f[idx] = v[r] + bv + resid[idx];
                }
            }
        }
    }
}

// ---------------- flash attention per (head, 128-row q-block) ----------------
// v2: LDS double-buffer + async reg-staged prefetch (T14), one barrier/tile,
//     XCD-aware head swizzle (per-XCD K/V working set = 4MB = L2), log2-domain
//     softmax with defer-max (T13, THR=8), cvt_pk P packing, setprio (T5).
// Swapped S^T = mfma(K, Q) so softmax row-reduce is in-lane + 2 shfl_xor.
// K/V^T/P LDS rows XOR-swizzled ((row&7)<<4) against 32-way conflicts (G4).
__global__ __launch_bounds__(256, 2) void k_attn(
    const unsigned short* __restrict__ qk,   // [8192][2048] bf16 (Q | K)
    const unsigned short* __restrict__ vT,   // [64 heads][128 d][1024 x] bf16
    unsigned short* __restrict__ ctx)        // [8192][1024] bf16
{
    __shared__ __align__(16) unsigned short Kl[2 * 64 * 128];   // [buf][x][d]
    __shared__ __align__(16) unsigned short Vl[2 * 128 * 64];   // [buf][d][x]
    __shared__ __align__(16) unsigned short Pl[128 * 64];       // [q][x]
    const int t = threadIdx.x;
    const int wave = t >> 6, lane = t & 63;
    const int lr = lane & 15, lg = lane >> 4;

    // XCD swizzle: consecutive linear block ids round-robin XCDs; give each
    // XCD 8 whole heads (8 qblks each) so its K/V set = 8 x 512KB = 4MB = L2.
    const int lid = blockIdx.y * gridDim.x + blockIdx.x;   // 0..511
    const int xcd = lid & 7, slot = lid >> 3;
    const int head = xcd * 8 + (slot & 7);   // bn*8 + h
    const int qblk = slot >> 3;              // 0..7

    const int h = head & 7;
    const int tok0 = (head >> 3) * 1024;
    const int qtok = tok0 + qblk * 128 + wave * 32;
    const float cl2 = 0.08838834764831845f * 1.44269504088896f;  // scale*log2(e)

    // Q fragments live in registers for the whole block (B-operand layout)
    bf16x8 qf[2][4];
#pragma unroll
    for (int nq = 0; nq < 2; ++nq)
#pragma unroll
        for (int kk = 0; kk < 4; ++kk)
            qf[nq][kk] = *(const bf16x8*)&qk[(size_t)(qtok + 16 * nq + lr) * 2048 + h * 128 + kk * 32 + lg * 8];

    f32x4 o[2][8];
#pragma unroll
    for (int a = 0; a < 2; ++a)
#pragma unroll
        for (int b = 0; b < 8; ++b)
            o[a][b] = (f32x4){0.f, 0.f, 0.f, 0.f};
    float m_run[2] = {-3.0e38f, -3.0e38f};   // log2 domain
    float l_run[2] = {0.f, 0.f};

    const unsigned short* vhead = &vT[(size_t)head * 128 * 1024];

    // per-thread staging coords (fixed across tiles)
    const int kx = t >> 2;                 // with i: row x = (i*256+t)>>4
    const int kc = t & 15;
    const int vd = t >> 1;                 // with i: row d = (i*256+t)>>3
    const int vc = t & 7;

    float4 rk[4], rv[4];
    // prologue: issue loads for tile 0
#pragma unroll
    for (int i = 0; i < 4; ++i) {
        int x = (i * 256 + t) >> 4;
        rk[i] = *(const float4*)&qk[(size_t)(tok0 + x) * 2048 + 1024 + h * 128 + kc * 8];
        int d = (i * 256 + t) >> 3;
        rv[i] = *(const float4*)&vhead[(size_t)d * 1024 + vc * 8];
    }

#pragma unroll 2
    for (int tile = 0; tile < 16; ++tile) {
        const int kb = (tile & 1) * 16384;   // byte offset of current buffer
        // write staged regs -> LDS buf[cur] (swizzled)
#pragma unroll
        for (int i = 0; i < 4; ++i) {
            int x = (i * 256 + t) >> 4;
            int byte = (x * 256 + kc * 16) ^ ((x & 7) << 4);
            *(float4*)((char*)Kl + kb + byte) = rk[i];
            int d = (i * 256 + t) >> 3;
            int vbyte = (d * 128 + vc * 16) ^ ((d & 7) << 4);
            *(float4*)((char*)Vl + kb + vbyte) = rv[i];
        }
        __syncthreads();
        // issue next tile's loads; they complete under this tile's compute
        if (tile < 15) {
            const int x0n = (tile + 1) * 64;
#pragma unroll
            for (int i = 0; i < 4; ++i) {
                int x = (i * 256 + t) >> 4;
                rk[i] = *(const float4*)&qk[(size_t)(tok0 + x0n + x) * 2048 + 1024 + h * 128 + kc * 8];
                int d = (i * 256 + t) >> 3;
                rv[i] = *(const float4*)&vhead[(size_t)d * 1024 + x0n + vc * 8];
            }
        }

        // S^T[x][q] = sum_d K[x][d] * Q[q][d]
        f32x4 s[4][2];
#pragma unroll
        for (int mi = 0; mi < 4; ++mi)
#pragma unroll
            for (int nq = 0; nq < 2; ++nq)
                s[mi][nq] = (f32x4){0.f, 0.f, 0.f, 0.f};
#pragma unroll
        for (int kk = 0; kk < 4; ++kk) {
            bf16x8 kf[4];
#pragma unroll
            for (int mi = 0; mi < 4; ++mi) {
                int row = mi * 16 + lr;
                int byte = (row * 256 + kk * 64 + lg * 16) ^ ((row & 7) << 4);
                kf[mi] = *(const bf16x8*)((const char*)Kl + kb + byte);
            }
            __builtin_amdgcn_s_setprio(1);
#pragma unroll
            for (int mi = 0; mi < 4; ++mi)
#pragma unroll
                for (int nq = 0; nq < 2; ++nq)
                    s[mi][nq] = __builtin_amdgcn_mfma_f32_16x16x32_bf16(kf[mi], qf[nq][kk], s[mi][nq], 0, 0, 0);
            __builtin_amdgcn_s_setprio(0);
        }

        // online softmax (log2 domain), defer-max: skip rescale unless
        // any q grew its max by >8 (P then bounded by 2^8; bf16-safe).
        float fac[2];
        bool doresc[2];
#pragma unroll
        for (int nq = 0; nq < 2; ++nq) {
            float mx = -3.0e38f;
#pragma unroll
            for (int mi = 0; mi < 4; ++mi)
#pragma unroll
                for (int r = 0; r < 4; ++r)
                    mx = fmaxf(mx, s[mi][nq][r]);
            mx = fmaxf(mx, __shfl_xor(mx, 16));
            mx = fmaxf(mx, __shfl_xor(mx, 32));
            float mxl = mx * cl2;
            float mr = m_run[nq];
            if (__any(mxl - mr > 8.0f)) {
                float mn = fmaxf(mr, mxl);
                fac[nq] = __builtin_amdgcn_exp2f(mr - mn);
                m_run[nq] = mn;
                doresc[nq] = true;
            } else {
                fac[nq] = 1.0f;
                doresc[nq] = false;
            }
            const float nmn = -m_run[nq];
            float sum = 0.f;
            const int q = wave * 32 + nq * 16 + lr;
#pragma unroll
            for (int mi = 0; mi < 4; ++mi) {
                float p0 = __builtin_amdgcn_exp2f(__builtin_fmaf(s[mi][nq][0], cl2, nmn));
                float p1 = __builtin_amdgcn_exp2f(__builtin_fmaf(s[mi][nq][1], cl2, nmn));
                float p2 = __builtin_amdgcn_exp2f(__builtin_fmaf(s[mi][nq][2], cl2, nmn));
                float p3 = __builtin_amdgcn_exp2f(__builtin_fmaf(s[mi][nq][3], cl2, nmn));
                sum += (p0 + p1) + (p2 + p3);
                uint2 pk;
                pk.x = cvt_pk_bf16(p0, p1);
                pk.y = cvt_pk_bf16(p2, p3);
                int byte = (q * 128 + (mi * 16 + lg * 4) * 2) ^ ((q & 7) << 4);
                *(uint2*)((char*)Pl + byte) = pk;  // 4 consecutive x, packed
            }
            sum += __shfl_xor(sum, 16);
            sum += __shfl_xor(sum, 32);
            l_run[nq] = l_run[nq] * fac[nq] + sum;
        }

        // rescale O only when max moved (wave-uniform branch)
#pragma unroll
        for (int mo = 0; mo < 2; ++mo)
            if (doresc[mo]) {
#pragma unroll
                for (int r = 0; r < 4; ++r) {
                    int src = (lane & 48) | (lg * 4 + r);
                    float f = __shfl(fac[mo], src);
#pragma unroll
                    for (int nd = 0; nd < 8; ++nd)
                        o[mo][nd][r] *= f;
                }
            }

        // O[q][d] += P[q][x] * V[x][d]  (intra-wave P reuse; same-wave DS order)
#pragma unroll
        for (int kk = 0; kk < 2; ++kk) {
            bf16x8 pf[2], vf[8];
#pragma unroll
            for (int mo = 0; mo < 2; ++mo) {
                int q = wave * 32 + mo * 16 + lr;
                int byte = (q * 128 + kk * 64 + lg * 16) ^ ((q & 7) << 4);
                pf[mo] = *(const bf16x8*)((const char*)Pl + byte);
            }
#pragma unroll
            for (int nd = 0; nd < 8; ++nd) {
                int drow = nd * 16 + lr;
                int byte = (drow * 128 + kk * 64 + lg * 16) ^ ((drow & 7) << 4);
                vf[nd] = *(const bf16x8*)((const char*)Vl + kb + byte);
            }
            __builtin_amdgcn_s_setprio(1);
#pragma unroll
            for (int mo = 0; mo < 2; ++mo)
#pragma unroll
                for (int nd = 0; nd < 8; ++nd)
                    o[mo][nd] = __builtin_amdgcn_mfma_f32_16x16x32_bf16(pf[mo], vf[nd], o[mo][nd], 0, 0, 0);
            __builtin_amdgcn_s_setprio(0);
        }
        // no trailing barrier: next iteration writes the OTHER K/V buffer,
        // whose last readers finished before the barrier we already passed.
    }

    // normalize + write ctx
#pragma unroll
    for (int mo = 0; mo < 2; ++mo) {
        float rl[4];
#pragma unroll
        for (int r = 0; r < 4; ++r) {
            int src = (lane & 48) | (lg * 4 + r);
            rl[r] = 1.0f / __shfl(l_run[mo], src);
        }
#pragma unroll
        for (int nd = 0; nd < 8; ++nd)
#pragma unroll
            for (int r = 0; r < 4; ++r) {
                int q = qtok + mo * 16 + lg * 4 + r;
                ctx[(size_t)q * 1024 + h * 128 + nd * 16 + lr] = f2bf(o[mo][nd][r] * rl[r]);
            }
    }
}

// ---------------- in-place LayerNorm over D=1024 ----------------
__global__ __launch_bounds__(256) void k_ln(float* __restrict__ io,
                                            const float* __restrict__ gamma,
                                            const float* __restrict__ beta)
{
    __shared__ float bs[4], bss[4];
    const int row = blockIdx.x;
    const int t = threadIdx.x;
    float4 v = ((const float4*)&io[(size_t)row * 1024])[t];
    float s = (v.x + v.y) + (v.z + v.w);
    float ss = (v.x * v.x + v.y * v.y) + (v.z * v.z + v.w * v.w);
#pragma unroll
    for (int off = 32; off >= 1; off >>= 1) {
        s += __shfl_xor(s, off);
        ss += __shfl_xor(ss, off);
    }
    if ((t & 63) == 0) { bs[t >> 6] = s; bss[t >> 6] = ss; }
    __syncthreads();
    s = (bs[0] + bs[1]) + (bs[2] + bs[3]);
    ss = (bss[0] + bss[1]) + (bss[2] + bss[3]);
    const float mu = s * (1.f / 1024.f);
    const float var = ss * (1.f / 1024.f) - mu * mu;
    const float rs = rsqrtf(var + 1e-5f);
    float4 g = ((const float4*)gamma)[t];
    float4 b = ((const float4*)beta)[t];
    float4 ov;
    ov.x = (v.x - mu) * rs * g.x + b.x;
    ov.y = (v.y - mu) * rs * g.y + b.y;
    ov.z = (v.z - mu) * rs * g.z + b.z;
    ov.w = (v.w - mu) * rs * g.w + b.w;
    ((float4*)&io[(size_t)row * 1024])[t] = ov;
}

extern "C" void kernel_launch(void* const* d_in, const int* in_sizes, int n_in,
                              void* d_out, int out_size, void* d_ws, size_t ws_size,
                              hipStream_t stream)
{
    const float* val   = (const float*)d_in[0];
    const float* w_qkv = (const float*)d_in[1];
    const float* b_qkv = (const float*)d_in[2];
    const float* w_out = (const float*)d_in[3];
    const float* b_out = (const float*)d_in[4];
    const float* ln_g  = (const float*)d_in[5];
    const float* ln_b  = (const float*)d_in[6];
    float* out = (float*)d_out;

    // workspace layout (92,274,688 bytes total)
    char* ws = (char*)d_ws;
    unsigned short* qk     = (unsigned short*)(ws + 0);          // 33,554,432 B [8192][2048]
    unsigned short* vTb    = (unsigned short*)(ws + 33554432);   // 16,777,216 B [64][128][1024]
    unsigned short* ctx    = (unsigned short*)(ws + 50331648);   // 16,777,216 B [8192][1024]
    unsigned short* w_outT = (unsigned short*)(ws + 67108864);   //  2,097,152 B [1024][1024]
    unsigned short* w_qkvT = (unsigned short*)(ws + 69206016);   //  6,291,456 B [3072][1024]
    unsigned short* valb   = (unsigned short*)(ws + 75497472);   // 16,777,216 B [8192][1024]

    k_convert<<<8192, 256, 0, stream>>>(val, valb, 2097152);
    k_transpose<<<dim3(48, 16), 256, 0, stream>>>(w_qkv, w_qkvT, 1024, 3072);
    k_transpose<<<dim3(16, 16), 256, 0, stream>>>(w_out, w_outT, 1024, 1024);
    k_gemm<0><<<dim3(24, 64), 256, 0, stream>>>(valb, w_qkvT, b_qkv, nullptr, qk, vTb, nullptr, 1024);
    k_attn<<<dim3(8, 64), 256, 0, stream>>>(qk, vTb, ctx);
    k_gemm<1><<<dim3(8, 64), 256, 0, stream>>>(ctx, w_outT, b_out, val, nullptr, nullptr, out, 1024);
    k_ln<<<8192, 256, 0, stream>>>(out, ln_g, ln_b);
}

// Round 3
// 175.774 us; speedup vs baseline: 1.2151x; 1.2151x over previous
//
#include <hip/hip_runtime.h>
#include <hip/hip_bf16.h>
#include <stdint.h>

// Problem: B=2, S=4096, D=1024, H=8, DH=128, W=1024, nb=4, M=B*S=8192
// Pipeline: convert/transpose -> GEMM1 (qkv, writes Q/K row-major + V transposed)
//           -> flash attention per (head, q-block) -> GEMM2 (+bias+residual -> d_out)
//           -> in-place LayerNorm.

typedef float f32x4 __attribute__((ext_vector_type(4)));
typedef __bf16 bf16x8 __attribute__((ext_vector_type(8)));

static __device__ __forceinline__ unsigned short f2bf(float f) {
    // round-to-nearest-even f32 -> bf16 (bit trick; inputs are finite)
    unsigned int u = __builtin_bit_cast(unsigned int, f);
    u += 0x7fffu + ((u >> 16) & 1u);
    return (unsigned short)(u >> 16);
}

static __device__ __forceinline__ unsigned cvt_pk_bf16(float lo, float hi) {
    unsigned r;
    asm("v_cvt_pk_bf16_f32 %0, %1, %2" : "=v"(r) : "v"(lo), "v"(hi));
    return r;  // low16 = bf16(lo), high16 = bf16(hi), RNE
}

static __device__ __forceinline__ void gload_lds16(const void* g, void* l) {
    __builtin_amdgcn_global_load_lds(
        (__attribute__((address_space(1))) void*)(g),
        (__attribute__((address_space(3))) void*)(l), 16, 0, 0);
}

#define VMCNT(n) asm volatile("s_waitcnt vmcnt(" #n ")" ::: "memory")

// ---------------- convert f32 -> bf16 (vectorized, G13) ----------------
__global__ __launch_bounds__(256) void k_convert(const float* __restrict__ in,
                                                 unsigned short* __restrict__ out,
                                                 int n4) {
    int i = blockIdx.x * 256 + threadIdx.x;
    if (i >= n4) return;
    float4 v = ((const float4*)in)[i];
    ushort4 o;
    o.x = f2bf(v.x); o.y = f2bf(v.y); o.z = f2bf(v.z); o.w = f2bf(v.w);
    ((ushort4*)out)[i] = o;
}

// ---------------- transpose f32 [R][C] -> bf16 [C][R] ----------------
__global__ __launch_bounds__(256) void k_transpose(const float* __restrict__ in,
                                                   unsigned short* __restrict__ out,
                                                   int R, int C) {
    __shared__ float tile[64][65];  // +1 pad: conflict-free column reads
    const int rt = blockIdx.y * 64, ct = blockIdx.x * 64;
    const int t = threadIdx.x;
#pragma unroll
    for (int i = 0; i < 4; ++i) {
        int fid = i * 256 + t;
        int r = fid >> 4;
        int c = (fid & 15) << 2;
        float4 v = *(const float4*)&in[(size_t)(rt + r) * C + ct + c];
        tile[r][c] = v.x; tile[r][c + 1] = v.y; tile[r][c + 2] = v.z; tile[r][c + 3] = v.w;
    }
    __syncthreads();
#pragma unroll
    for (int i = 0; i < 4; ++i) {
        int fid = i * 256 + t;
        int c = fid >> 4;
        int r0 = (fid & 15) << 2;
        ushort4 o;
        o.x = f2bf(tile[r0][c]);     o.y = f2bf(tile[r0 + 1][c]);
        o.z = f2bf(tile[r0 + 2][c]); o.w = f2bf(tile[r0 + 3][c]);
        *(ushort4*)&out[(size_t)(ct + c) * R + rt + r0] = o;
    }
}

// ---------------- m97-style bf16 GEMM: C = A[M][K] * Bt[N][K]^T ----------------
// MODE 0: qkv projection. n<2048 -> out_qk row-major; n>=2048 -> V written
//         transposed into out_vT[head][d][x] (packed ushort4 along x).
// MODE 1: out projection. out_f[idx] = acc + bias[n] + resid[idx]  (fp32)
template <int MODE>
__global__ __launch_bounds__(256, 2) void k_gemm(
    const unsigned short* __restrict__ A,
    const unsigned short* __restrict__ Bt,
    const float* __restrict__ bias,
    const float* __restrict__ resid,
    unsigned short* __restrict__ out_qk,
    unsigned short* __restrict__ out_vT,
    float* __restrict__ out_f,
    int Kdim)
{
    __shared__ __align__(16) unsigned short Al[128 * 64];  // [m][k] linear (global_load_lds)
    __shared__ __align__(16) unsigned short Bl[128 * 64];  // [n][k] linear
    const int t = threadIdx.x;
    const int wave = t >> 6, lane = t & 63;
    const int wm = wave >> 1, wn = wave & 1;
    const int lr = lane & 15, lg = lane >> 4;
    const int tile_m = blockIdx.y * 128;
    const int tile_n = blockIdx.x * 128;

    f32x4 acc[4][4];
#pragma unroll
    for (int i = 0; i < 4; ++i)
#pragma unroll
        for (int j = 0; j < 4; ++j)
            acc[i][j] = (f32x4){0.f, 0.f, 0.f, 0.f};

    const int srow = lane >> 3;          // 0..7 rows within 1KB chunk
    const int scol = (lane & 7) * 8;     // 8 bf16 = 16B per lane

    for (int kt = 0; kt < Kdim; kt += 64) {
#pragma unroll
        for (int i = 0; i < 4; ++i) {
            int chunk = i * 4 + wave;            // 16 chunks of 1KB (8 rows x 128B)
            int row = chunk * 8 + srow;
            gload_lds16(&A[(size_t)(tile_m + row) * Kdim + kt + scol], &Al[chunk * 512]);
            gload_lds16(&Bt[(size_t)(tile_n + row) * Kdim + kt + scol], &Bl[chunk * 512]);
        }
        __syncthreads();
#pragma unroll
        for (int kk = 0; kk < 2; ++kk) {
            bf16x8 af[4], bfr[4];
#pragma unroll
            for (int mi = 0; mi < 4; ++mi)
                af[mi] = *(const bf16x8*)&Al[(wm * 64 + mi * 16 + lr) * 64 + kk * 32 + lg * 8];
#pragma unroll
            for (int ni = 0; ni < 4; ++ni)
                bfr[ni] = *(const bf16x8*)&Bl[(wn * 64 + ni * 16 + lr) * 64 + kk * 32 + lg * 8];
#pragma unroll
            for (int mi = 0; mi < 4; ++mi)
#pragma unroll
                for (int ni = 0; ni < 4; ++ni)
                    acc[mi][ni] = __builtin_amdgcn_mfma_f32_16x16x32_bf16(af[mi], bfr[ni], acc[mi][ni], 0, 0, 0);
        }
        __syncthreads();
    }

    // epilogue: D row = (lane>>4)*4 + r, col = lane&15 (measured m89/m91 layout)
#pragma unroll
    for (int ni = 0; ni < 4; ++ni) {
        int n = tile_n + wn * 64 + ni * 16 + lr;
        float bv = bias[n];
#pragma unroll
        for (int mi = 0; mi < 4; ++mi) {
            int m0 = tile_m + wm * 64 + mi * 16 + lg * 4;
            f32x4 v = acc[mi][ni];
            if (MODE == 0) {
                if (n < 2048) {          // Q,K region: row-major [m][2048]
#pragma unroll
                    for (int r = 0; r < 4; ++r)
                        out_qk[(size_t)(m0 + r) * 2048 + n] = f2bf(v[r] + bv);
                } else {                 // V region: write transposed [head][d][x]
                    int hd = (n - 2048) >> 7;
                    int dd = (n - 2048) & 127;
                    int bn = m0 >> 10;           // window index b*nb+nblk
                    int x0 = m0 & 1023;          // token-in-window; 4 consecutive
                    ushort4 o;
                    o.x = f2bf(v[0] + bv); o.y = f2bf(v[1] + bv);
                    o.z = f2bf(v[2] + bv); o.w = f2bf(v[3] + bv);
                    *(ushort4*)&out_vT[((size_t)(bn * 8 + hd) * 128 + dd) * 1024 + x0] = o;
                }
            } else {
#pragma unroll
                for (int r = 0; r < 4; ++r) {
                    size_t idx = (size_t)(m0 + r) * 1024 + n;
                    out_f[idx] = v[r] + bv + resid[idx];
                }
            }
        }
    }
}

// ---------------- flash attention per (head, 128-row q-block) ----------------
// v3: K/V prefetch via global_load_lds into double-buffered LDS with COUNTED
//     vmcnt (T3/T4, m201 mechanism): tile t+1's loads stay in flight across
//     the barrier and complete under tile t's compute. Zero register cost
//     (v2's reg-staged prefetch spilled -> 170MB scratch writes).
//     Swizzle per rule #21: linear LDS dest + inverse-swizzled global SOURCE
//     (XOR involution on 16B-block index) + swizzled READ.
// XCD-aware head swizzle keeps each XCD's K/V set = 4MB = its L2 (kept: FETCH
// 139->40MB). Log2-domain softmax + defer-max (T13), cvt_pk P pack, setprio.
__global__ __launch_bounds__(256, 2) void k_attn(
    const unsigned short* __restrict__ qk,   // [8192][2048] bf16 (Q | K)
    const unsigned short* __restrict__ vT,   // [64 heads][128 d][1024 x] bf16
    unsigned short* __restrict__ ctx)        // [8192][1024] bf16
{
    __shared__ __align__(16) unsigned short Kl[2 * 64 * 128];   // [buf][x][d]
    __shared__ __align__(16) unsigned short Vl[2 * 128 * 64];   // [buf][d][x]
    __shared__ __align__(16) unsigned short Pl[128 * 64];       // [q][x]
    const int t = threadIdx.x;
    const int wave = t >> 6, lane = t & 63;
    const int lr = lane & 15, lg = lane >> 4;

    // XCD swizzle: linear ids round-robin XCDs; give each XCD 8 whole heads
    // (8 qblks each) so its K/V working set = 8 x 512KB = 4MB = L2.
    const int lid = blockIdx.y * gridDim.x + blockIdx.x;   // 0..511
    const int xcd = lid & 7, slot = lid >> 3;
    const int head = xcd * 8 + (slot & 7);   // bn*8 + h
    const int qblk = slot >> 3;              // 0..7

    const int h = head & 7;
    const int tok0 = (head >> 3) * 1024;
    const int qtok = tok0 + qblk * 128 + wave * 32;
    const float cl2 = 0.08838834764831845f * 1.44269504088896f;  // scale*log2(e)

    const unsigned short* kbase = &qk[(size_t)tok0 * 2048 + 1024 + h * 128];
    const unsigned short* vhead = &vT[(size_t)head * 128 * 1024];

    // ---- prefetch staging: 8 x global_load_lds(16B) per tile ----
    // K: LDS byte L=i*4096+w*1024+l*16 must hold row x=L>>8, in-row block
    //    ((L>>4)&15)^(x&7)  -> load global block c = (l&15)^(x&7).
    // V: rows of 128B: d=L>>7, block c=(l&7)^(d&7).
    auto stage = [&](int x0, int buf) {
        unsigned short* Kb = (unsigned short*)((char*)Kl + buf * 16384);
        unsigned short* Vb = (unsigned short*)((char*)Vl + buf * 16384);
#pragma unroll
        for (int i = 0; i < 4; ++i) {
            int x = i * 16 + wave * 4 + (lane >> 4);
            int ck = (lane & 15) ^ (x & 7);
            gload_lds16(&kbase[(size_t)(x0 + x) * 2048 + ck * 8], &Kb[i * 2048 + wave * 512]);
            int d = i * 32 + wave * 8 + (lane >> 3);
            int cv = (lane & 7) ^ (d & 7);
            gload_lds16(&vhead[(size_t)d * 1024 + x0 + cv * 8], &Vb[i * 2048 + wave * 512]);
        }
    };

    // Q fragments live in registers for the whole block (B-operand layout)
    bf16x8 qf[2][4];
#pragma unroll
    for (int nq = 0; nq < 2; ++nq)
#pragma unroll
        for (int kk = 0; kk < 4; ++kk)
            qf[nq][kk] = *(const bf16x8*)&qk[(size_t)(qtok + 16 * nq + lr) * 2048 + h * 128 + kk * 32 + lg * 8];

    f32x4 o[2][8];
#pragma unroll
    for (int a = 0; a < 2; ++a)
#pragma unroll
        for (int b = 0; b < 8; ++b)
            o[a][b] = (f32x4){0.f, 0.f, 0.f, 0.f};
    float m_run[2] = {-3.0e38f, -3.0e38f};   // log2 domain
    float l_run[2] = {0.f, 0.f};

    stage(0, 0);   // tile 0 in flight

    for (int tile = 0; tile < 16; ++tile) {
        const int kb = (tile & 1) * 16384;   // byte offset of current buffer
        // issue next tile's loads; they complete under THIS tile's compute
        if (tile < 15) {
            stage((tile + 1) * 64, (tile + 1) & 1);
            VMCNT(8);          // wait only for tile's own 8; keep 8 in flight
        } else {
            VMCNT(0);
        }
        __builtin_amdgcn_sched_barrier(0);
        __builtin_amdgcn_s_barrier();        // everyone's tile data visible
        __builtin_amdgcn_sched_barrier(0);

        // S^T[x][q] = sum_d K[x][d] * Q[q][d]
        f32x4 s[4][2];
#pragma unroll
        for (int mi = 0; mi < 4; ++mi)
#pragma unroll
            for (int nq = 0; nq < 2; ++nq)
                s[mi][nq] = (f32x4){0.f, 0.f, 0.f, 0.f};
#pragma unroll
        for (int kk = 0; kk < 4; ++kk) {
            bf16x8 kf[4];
#pragma unroll
            for (int mi = 0; mi < 4; ++mi) {
                int row = mi * 16 + lr;
                int byte = (row * 256 + kk * 64 + lg * 16) ^ ((row & 7) << 4);
                kf[mi] = *(const bf16x8*)((const char*)Kl + kb + byte);
            }
            __builtin_amdgcn_s_setprio(1);
#pragma unroll
            for (int mi = 0; mi < 4; ++mi)
#pragma unroll
                for (int nq = 0; nq < 2; ++nq)
                    s[mi][nq] = __builtin_amdgcn_mfma_f32_16x16x32_bf16(kf[mi], qf[nq][kk], s[mi][nq], 0, 0, 0);
            __builtin_amdgcn_s_setprio(0);
        }

        // online softmax (log2 domain), defer-max: skip rescale unless
        // any q grew its max by >8 (P then bounded by 2^8; bf16-safe).
        float fac[2];
        bool doresc[2];
#pragma unroll
        for (int nq = 0; nq < 2; ++nq) {
            float mx = -3.0e38f;
#pragma unroll
            for (int mi = 0; mi < 4; ++mi)
#pragma unroll
                for (int r = 0; r < 4; ++r)
                    mx = fmaxf(mx, s[mi][nq][r]);
            mx = fmaxf(mx, __shfl_xor(mx, 16));
            mx = fmaxf(mx, __shfl_xor(mx, 32));
            float mxl = mx * cl2;
            float mr = m_run[nq];
            if (__any(mxl - mr > 8.0f)) {
                float mn = fmaxf(mr, mxl);
                fac[nq] = __builtin_amdgcn_exp2f(mr - mn);
                m_run[nq] = mn;
                doresc[nq] = true;
            } else {
                fac[nq] = 1.0f;
                doresc[nq] = false;
            }
            const float nmn = -m_run[nq];
            float sum = 0.f;
            const int q = wave * 32 + nq * 16 + lr;
#pragma unroll
            for (int mi = 0; mi < 4; ++mi) {
                float p0 = __builtin_amdgcn_exp2f(__builtin_fmaf(s[mi][nq][0], cl2, nmn));
                float p1 = __builtin_amdgcn_exp2f(__builtin_fmaf(s[mi][nq][1], cl2, nmn));
                float p2 = __builtin_amdgcn_exp2f(__builtin_fmaf(s[mi][nq][2], cl2, nmn));
                float p3 = __builtin_amdgcn_exp2f(__builtin_fmaf(s[mi][nq][3], cl2, nmn));
                sum += (p0 + p1) + (p2 + p3);
                uint2 pk;
                pk.x = cvt_pk_bf16(p0, p1);
                pk.y = cvt_pk_bf16(p2, p3);
                int byte = (q * 128 + (mi * 16 + lg * 4) * 2) ^ ((q & 7) << 4);
                *(uint2*)((char*)Pl + byte) = pk;  // 4 consecutive x, packed
            }
            sum += __shfl_xor(sum, 16);
            sum += __shfl_xor(sum, 32);
            l_run[nq] = l_run[nq] * fac[nq] + sum;
        }

        // rescale O only when max moved (wave-uniform branch)
#pragma unroll
        for (int mo = 0; mo < 2; ++mo)
            if (doresc[mo]) {
#pragma unroll
                for (int r = 0; r < 4; ++r) {
                    int src = (lane & 48) | (lg * 4 + r);
                    float f = __shfl(fac[mo], src);
#pragma unroll
                    for (int nd = 0; nd < 8; ++nd)
                        o[mo][nd][r] *= f;
                }
            }

        // O[q][d] += P[q][x] * V[x][d]  (P is intra-wave: no barrier needed)
#pragma unroll
        for (int kk = 0; kk < 2; ++kk) {
            bf16x8 pf[2], vf[8];
#pragma unroll
            for (int mo = 0; mo < 2; ++mo) {
                int q = wave * 32 + mo * 16 + lr;
                int byte = (q * 128 + kk * 64 + lg * 16) ^ ((q & 7) << 4);
                pf[mo] = *(const bf16x8*)((const char*)Pl + byte);
            }
#pragma unroll
            for (int nd = 0; nd < 8; ++nd) {
                int drow = nd * 16 + lr;
                int byte = (drow * 128 + kk * 64 + lg * 16) ^ ((drow & 7) << 4);
                vf[nd] = *(const bf16x8*)((const char*)Vl + kb + byte);
            }
            __builtin_amdgcn_s_setprio(1);
#pragma unroll
            for (int mo = 0; mo < 2; ++mo)
#pragma unroll
                for (int nd = 0; nd < 8; ++nd)
                    o[mo][nd] = __builtin_amdgcn_mfma_f32_16x16x32_bf16(pf[mo], vf[nd], o[mo][nd], 0, 0, 0);
            __builtin_amdgcn_s_setprio(0);
        }
        // tail barrier: all waves done reading buf[tile&1] before the NEXT
        // iteration issues gloads into buf[(tile+2)&1]... and, crucially,
        // before iteration tile+1 issues into buf[(tile+1)&1]'s sibling.
        __builtin_amdgcn_s_barrier();
        __builtin_amdgcn_sched_barrier(0);
    }

    // normalize + write ctx
#pragma unroll
    for (int mo = 0; mo < 2; ++mo) {
        float rl[4];
#pragma unroll
        for (int r = 0; r < 4; ++r) {
            int src = (lane & 48) | (lg * 4 + r);
            rl[r] = 1.0f / __shfl(l_run[mo], src);
        }
#pragma unroll
        for (int nd = 0; nd < 8; ++nd)
#pragma unroll
            for (int r = 0; r < 4; ++r) {
                int q = qtok + mo * 16 + lg * 4 + r;
                ctx[(size_t)q * 1024 + h * 128 + nd * 16 + lr] = f2bf(o[mo][nd][r] * rl[r]);
            }
    }
}

// ---------------- in-place LayerNorm over D=1024 ----------------
__global__ __launch_bounds__(256) void k_ln(float* __restrict__ io,
                                            const float* __restrict__ gamma,
                                            const float* __restrict__ beta)
{
    __shared__ float bs[4], bss[4];
    const int row = blockIdx.x;
    const int t = threadIdx.x;
    float4 v = ((const float4*)&io[(size_t)row * 1024])[t];
    float s = (v.x + v.y) + (v.z + v.w);
    float ss = (v.x * v.x + v.y * v.y) + (v.z * v.z + v.w * v.w);
#pragma unroll
    for (int off = 32; off >= 1; off >>= 1) {
        s += __shfl_xor(s, off);
        ss += __shfl_xor(ss, off);
    }
    if ((t & 63) == 0) { bs[t >> 6] = s; bss[t >> 6] = ss; }
    __syncthreads();
    s = (bs[0] + bs[1]) + (bs[2] + bs[3]);
    ss = (bss[0] + bss[1]) + (bss[2] + bss[3]);
    const float mu = s * (1.f / 1024.f);
    const float var = ss * (1.f / 1024.f) - mu * mu;
    const float rs = rsqrtf(var + 1e-5f);
    float4 g = ((const float4*)gamma)[t];
    float4 b = ((const float4*)beta)[t];
    float4 ov;
    ov.x = (v.x - mu) * rs * g.x + b.x;
    ov.y = (v.y - mu) * rs * g.y + b.y;
    ov.z = (v.z - mu) * rs * g.z + b.z;
    ov.w = (v.w - mu) * rs * g.w + b.w;
    ((float4*)&io[(size_t)row * 1024])[t] = ov;
}

extern "C" void kernel_launch(void* const* d_in, const int* in_sizes, int n_in,
                              void* d_out, int out_size, void* d_ws, size_t ws_size,
                              hipStream_t stream)
{
    const float* val   = (const float*)d_in[0];
    const float* w_qkv = (const float*)d_in[1];
    const float* b_qkv = (const float*)d_in[2];
    const float* w_out = (const float*)d_in[3];
    const float* b_out = (const float*)d_in[4];
    const float* ln_g  = (const float*)d_in[5];
    const float* ln_b  = (const float*)d_in[6];
    float* out = (float*)d_out;

    // workspace layout (92,274,688 bytes total)
    char* ws = (char*)d_ws;
    unsigned short* qk     = (unsigned short*)(ws + 0);          // 33,554,432 B [8192][2048]
    unsigned short* vTb    = (unsigned short*)(ws + 33554432);   // 16,777,216 B [64][128][1024]
    unsigned short* ctx    = (unsigned short*)(ws + 50331648);   // 16,777,216 B [8192][1024]
    unsigned short* w_outT = (unsigned short*)(ws + 67108864);   //  2,097,152 B [1024][1024]
    unsigned short* w_qkvT = (unsigned short*)(ws + 69206016);   //  6,291,456 B [3072][1024]
    unsigned short* valb   = (unsigned short*)(ws + 75497472);   // 16,777,216 B [8192][1024]

    k_convert<<<8192, 256, 0, stream>>>(val, valb, 2097152);
    k_transpose<<<dim3(48, 16), 256, 0, stream>>>(w_qkv, w_qkvT, 1024, 3072);
    k_transpose<<<dim3(16, 16), 256, 0, stream>>>(w_out, w_outT, 1024, 1024);
    k_gemm<0><<<dim3(24, 64), 256, 0, stream>>>(valb, w_qkvT, b_qkv, nullptr, qk, vTb, nullptr, 1024);
    k_attn<<<dim3(8, 64), 256, 0, stream>>>(qk, vTb, ctx);
    k_gemm<1><<<dim3(8, 64), 256, 0, stream>>>(ctx, w_outT, b_out, val, nullptr, nullptr, out, 1024);
    k_ln<<<8192, 256, 0, stream>>>(out, ln_g, ln_b);
}